// Round 9
// baseline (460.014 us; speedup 1.0000x reference)
//
#include <hip/hip_runtime.h>
#include <math.h>

#define N_NODES   100000
#define N_EDGES   1600000
#define NODE_F    128
#define EDGE_F    128
#define GLOB_F    64
#define N_GRAPHS  256
#define HIDDEN    128
#define IN_DIM    320   // 128 + 128 + 64

#define SCAN_CHUNK 2048
#define NSCAN ((N_NODES + SCAN_CHUNK - 1) / SCAN_CHUNK)   // 49

typedef __bf16 bf16x8 __attribute__((ext_vector_type(8)));
typedef __bf16 bf16x4 __attribute__((ext_vector_type(4)));
typedef float  f32x4  __attribute__((ext_vector_type(4)));

__device__ __forceinline__ void cvt_store4(__bf16* p, float x, float y, float z, float w) {
    bf16x4 b = { (__bf16)x, (__bf16)y, (__bf16)z, (__bf16)w };
    *reinterpret_cast<bf16x4*>(p) = b;
}

// ---------------------------------------------------------------------------
// W (f32 [128,320]) -> bf16, once.  (kept separate — round-6 proven config)
// ---------------------------------------------------------------------------
__global__ __launch_bounds__(256) void wbf_kernel(const float* __restrict__ W,
                                                  __bf16* __restrict__ wbf) {
    int i = blockIdx.x * 256 + threadIdx.x;   // 160 blocks x 256 = 40960 exact
    wbf[i] = (__bf16)W[i];
}

// ---------------------------------------------------------------------------
// CSR build: histogram -> 3-kernel scan -> cursor-atomic fill (round-6 verbatim)
// ---------------------------------------------------------------------------
__global__ __launch_bounds__(256) void hist_kernel(const int* __restrict__ dst,
                                                   int* __restrict__ counts) {
    int i = blockIdx.x * 256 + threadIdx.x;   // 6250 x 256 = 1.6M exact
    if (i < N_EDGES) atomicAdd(&counts[dst[i]], 1);
}

__global__ __launch_bounds__(256) void scan1_kernel(const int* __restrict__ counts,
                                                    int* __restrict__ partial) {
    __shared__ int red[256];
    int tid = threadIdx.x;
    int base = blockIdx.x * SCAN_CHUNK + tid * 8;
    int s = 0;
    #pragma unroll
    for (int j = 0; j < 8; ++j) {
        int idx = base + j;
        if (idx < N_NODES) s += counts[idx];
    }
    red[tid] = s;
    __syncthreads();
    for (int off = 128; off > 0; off >>= 1) {
        if (tid < off) red[tid] += red[tid + off];
        __syncthreads();
    }
    if (tid == 0) partial[blockIdx.x] = red[0];
}

__global__ __launch_bounds__(64) void scan2_kernel(const int* __restrict__ partial,
                                                   int* __restrict__ pscan) {
    if (threadIdx.x == 0) {
        int run = 0;
        for (int b = 0; b < NSCAN; ++b) { pscan[b] = run; run += partial[b]; }
    }
}

__global__ __launch_bounds__(256) void scan3_kernel(const int* __restrict__ counts,
                                                    const int* __restrict__ pscan,
                                                    int* __restrict__ offs,
                                                    int* __restrict__ cursor) {
    __shared__ int ts[256];
    int tid = threadIdx.x;
    int base = blockIdx.x * SCAN_CHUNK + tid * 8;
    int c[8];
    int tot = 0;
    #pragma unroll
    for (int j = 0; j < 8; ++j) {
        int idx = base + j;
        c[j] = (idx < N_NODES) ? counts[idx] : 0;
        tot += c[j];
    }
    ts[tid] = tot;
    __syncthreads();
    for (int off = 1; off < 256; off <<= 1) {
        int v = 0;
        if (tid >= off) v = ts[tid - off];
        __syncthreads();
        if (tid >= off) ts[tid] += v;
        __syncthreads();
    }
    int run = pscan[blockIdx.x] + ts[tid] - tot;   // exclusive prefix
    #pragma unroll
    for (int j = 0; j < 8; ++j) {
        int idx = base + j;
        if (idx < N_NODES) { offs[idx] = run; cursor[idx] = run; run += c[j]; }
    }
    if (blockIdx.x == 0 && tid == 0) offs[N_NODES] = N_EDGES;
}

__global__ __launch_bounds__(256) void fill_kernel(const int* __restrict__ dst,
                                                   int* __restrict__ cursor,
                                                   int* __restrict__ eid) {
    int i = blockIdx.x * 256 + threadIdx.x;
    if (i < N_EDGES) {
        int d = dst[i];
        int pos = atomicAdd(&cursor[d], 1);
        eid[pos] = i;
    }
}

// ---------------------------------------------------------------------------
// Gather-mean kernel: 32-lane groups (2 nodes/wave), NO launch bounds
// (rounds 7/8 proved any VGPR cap kills the load pipeline). Each lane covers
// 16B of the 512B edge row -> 1 load per edge, 32 edges in flight per group.
// vs round 6 (16-lane groups): same bytes/coalescing, but wave straggler time
// is max(deg) over 2 nodes instead of 4. Writes mean as bf16 [N_NODES,128].
// ---------------------------------------------------------------------------
__global__ void gather_kernel(
    const float* __restrict__ edge_feats,   // [N_EDGES,128]
    const int*   __restrict__ offs,         // [N_NODES+1]
    const int*   __restrict__ eid,          // [N_EDGES]
    __bf16* __restrict__ mean_bf)           // [N_NODES,128]
{
    const int tid  = threadIdx.x;
    const int lane = tid & 63;
    const int g32  = lane & 31;             // lane within 32-group
    const int base = lane & 32;             // group base for shfl
    const int n    = blockIdx.x * 8 + (tid >> 5);   // node id, 12500 blocks exact

    const int beg = offs[n], end = offs[n + 1];
    const int E   = end - beg;
    const int lim = max(end - 1, 0);
    int ev = eid[min(beg + g32, lim)];      // 32 eids in flight

    float a0 = 0.f, a1 = 0.f, a2 = 0.f, a3 = 0.f;
    for (int c0 = 0; c0 < E; c0 += 32) {
        #pragma unroll
        for (int i = 0; i < 32; ++i) {
            int e = __shfl(ev, base + i);
            if (c0 + i < E) {
                f32x4 u = *reinterpret_cast<const f32x4*>(
                    edge_feats + (size_t)e * EDGE_F + g32 * 4);
                a0 += u.x; a1 += u.y; a2 += u.z; a3 += u.w;
            }
        }
        ev = eid[min(beg + c0 + 32 + g32, lim)];
    }
    float ic = 1.0f / fmaxf((float)E, 1.0f);
    bf16x4 b;
    b[0] = (__bf16)(a0 * ic); b[1] = (__bf16)(a1 * ic);
    b[2] = (__bf16)(a2 * ic); b[3] = (__bf16)(a3 * ic);
    *reinterpret_cast<bf16x4*>(mean_bf + (size_t)n * EDGE_F + g32 * 4) = b;
}

// ---------------------------------------------------------------------------
// GEMM kernel: concat (node f32->bf16, mean bf16 copy, glob f32->bf16) into
// LDS, barrier-free MFMA k-loop (B direct from L2-resident bf16 W), shifted
// softplus epilogue. Block = 256 threads (4 waves), 32 rows x 128 cols.
// ---------------------------------------------------------------------------
#define ROWS 32
#define XSTR (IN_DIM + 8)     // 328 bf16 -> 656 B row stride (16B-aligned)

__global__ __launch_bounds__(256) void gemm_kernel(
    const float* __restrict__ node_feats,   // [N_NODES,128]
    const __bf16* __restrict__ mean_bf,     // [N_NODES,128]
    const float* __restrict__ glob,         // [256,64]
    const int*   __restrict__ batch,        // [N_NODES]
    const __bf16* __restrict__ wbf,         // [128,320] bf16
    float* __restrict__ out)                // [N_NODES,128]
{
    __shared__ __bf16 xs[ROWS * XSTR];      // 20992 B

    const int tid  = threadIdx.x;
    const int row0 = blockIdx.x * ROWS;
    const int wv   = tid >> 6;
    const int lane = tid & 63;

    // ---- stage node features -> xs[:, 0:128)
    #pragma unroll
    for (int it = 0; it < 4; ++it) {
        int i = tid + it * 256;             // 0..1023
        int r = i >> 5, k4 = i & 31;
        float4 v = *reinterpret_cast<const float4*>(
            node_feats + (size_t)(row0 + r) * NODE_F + k4 * 4);
        cvt_store4(&xs[r * XSTR + k4 * 4], v.x, v.y, v.z, v.w);
    }
    // ---- stage mean (already bf16) -> xs[:, 128:256)
    #pragma unroll
    for (int it = 0; it < 2; ++it) {
        int i = tid + it * 256;             // 0..511
        int r = i >> 4, c = i & 15;
        bf16x8 v = *reinterpret_cast<const bf16x8*>(
            mean_bf + (size_t)(row0 + r) * EDGE_F + c * 8);
        *reinterpret_cast<bf16x8*>(&xs[r * XSTR + NODE_F + c * 8]) = v;
    }
    // ---- stage globals -> xs[:, 256:320)
    #pragma unroll
    for (int it = 0; it < 2; ++it) {
        int i = tid + it * 256;             // 0..511
        int r = i >> 4, k4 = i & 15;
        int b = batch[row0 + r];
        float4 v = *reinterpret_cast<const float4*>(
            glob + (size_t)b * GLOB_F + k4 * 4);
        cvt_store4(&xs[r * XSTR + NODE_F + EDGE_F + k4 * 4], v.x, v.y, v.z, v.w);
    }

    __syncthreads();   // xs complete; k-loop below is barrier-free

    f32x4 acc00 = {0.f, 0.f, 0.f, 0.f};
    f32x4 acc10 = {0.f, 0.f, 0.f, 0.f};
    f32x4 acc01 = {0.f, 0.f, 0.f, 0.f};
    f32x4 acc11 = {0.f, 0.f, 0.f, 0.f};

    const int lr = lane & 15;    // row/col within MFMA tile
    const int kb = lane >> 4;    // k-block of 8

    const __bf16* wrow0 = wbf + (size_t)(wv * 32 + lr) * IN_DIM + kb * 8;
    const __bf16* wrow1 = wrow0 + 16 * IN_DIM;

    #pragma unroll 2
    for (int kt = 0; kt < IN_DIM / 32; ++kt) {     // 10 k-steps
        bf16x8 a0 = *reinterpret_cast<const bf16x8*>(&xs[lr * XSTR + kt * 32 + kb * 8]);
        bf16x8 a1 = *reinterpret_cast<const bf16x8*>(&xs[(16 + lr) * XSTR + kt * 32 + kb * 8]);
        bf16x8 b0 = *reinterpret_cast<const bf16x8*>(wrow0 + kt * 32);
        bf16x8 b1 = *reinterpret_cast<const bf16x8*>(wrow1 + kt * 32);

        acc00 = __builtin_amdgcn_mfma_f32_16x16x32_bf16(a0, b0, acc00, 0, 0, 0);
        acc10 = __builtin_amdgcn_mfma_f32_16x16x32_bf16(a1, b0, acc10, 0, 0, 0);
        acc01 = __builtin_amdgcn_mfma_f32_16x16x32_bf16(a0, b1, acc01, 0, 0, 0);
        acc11 = __builtin_amdgcn_mfma_f32_16x16x32_bf16(a1, b1, acc11, 0, 0, 0);
    }

    // ---- epilogue: shifted softplus, C/D layout col=lane&15, row=(lane>>4)*4+q
    const float LN2 = 0.69314718055994530942f;
#define EMIT(ACC, RT, CT)                                                      \
    do {                                                                       \
        int col = (wv * 2 + (CT)) * 16 + lr;                                   \
        _Pragma("unroll")                                                      \
        for (int q = 0; q < 4; ++q) {                                          \
            int row = row0 + (RT) * 16 + kb * 4 + q;                           \
            float h = ACC[q];                                                  \
            float sp = fmaxf(h, 0.f) + log1pf(__expf(-fabsf(h)));              \
            out[(size_t)row * HIDDEN + col] = sp - LN2;                        \
        }                                                                      \
    } while (0)
    EMIT(acc00, 0, 0);
    EMIT(acc10, 1, 0);
    EMIT(acc01, 0, 1);
    EMIT(acc11, 1, 1);
#undef EMIT
}

// ---------------------------------------------------------------------------
extern "C" void kernel_launch(void* const* d_in, const int* in_sizes, int n_in,
                              void* d_out, int out_size, void* d_ws, size_t ws_size,
                              hipStream_t stream) {
    const float* node_feats = (const float*)d_in[0];   // [100000,128]
    const float* edge_feats = (const float*)d_in[1];   // [1600000,128]
    const float* glob       = (const float*)d_in[2];   // [256,64]
    const float* W          = (const float*)d_in[3];   // [128,320]
    const int*   edge_index = (const int*)d_in[4];     // [2,1600000]
    const int*   batch      = (const int*)d_in[5];     // [100000]
    float* out = (float*)d_out;                        // [100000,128]

    const int* dst = edge_index + N_EDGES;             // row 1 = destinations

    // workspace layout (16B-aligned chunks)
    __bf16* wbf     = (__bf16*)d_ws;                              // 81,920 B
    __bf16* mean_bf = (__bf16*)((char*)d_ws + 81920);             // 25,600,000 B
    int* ws_i       = (int*)((char*)d_ws + 81920 + 25600000);
    int* counts  = ws_i;                               // 100000
    int* partial = ws_i + 100000;                      // 64
    int* pscan   = ws_i + 100064;                      // 64
    int* offs    = ws_i + 100128;                      // 100001
    int* cursor  = ws_i + 200132;                      // 100000
    int* eid     = ws_i + 300132;                      // 1600000  (ends ~33 MB)

    hipMemsetAsync(counts, 0, (size_t)N_NODES * sizeof(int), stream);

    wbf_kernel<<<160, 256, 0, stream>>>(W, wbf);
    hist_kernel<<<N_EDGES / 256, 256, 0, stream>>>(dst, counts);
    scan1_kernel<<<NSCAN, 256, 0, stream>>>(counts, partial);
    scan2_kernel<<<1, 64, 0, stream>>>(partial, pscan);
    scan3_kernel<<<NSCAN, 256, 0, stream>>>(counts, pscan, offs, cursor);
    fill_kernel<<<N_EDGES / 256, 256, 0, stream>>>(dst, cursor, eid);

    gather_kernel<<<N_NODES / 8, 256, 0, stream>>>(edge_feats, offs, eid, mean_bf);

    gemm_kernel<<<N_NODES / ROWS, 256, 0, stream>>>(
        node_feats, mean_bf, glob, batch, wbf, out);
}

// Round 10
// 454.241 us; speedup vs baseline: 1.0127x; 1.0127x over previous
//
#include <hip/hip_runtime.h>
#include <math.h>

#define N_NODES   100000
#define N_EDGES   1600000
#define NODE_F    128
#define EDGE_F    128
#define GLOB_F    64
#define N_GRAPHS  256
#define HIDDEN    128
#define IN_DIM    320   // 128 + 128 + 64

#define SCAN_CHUNK 2048
#define NSCAN ((N_NODES + SCAN_CHUNK - 1) / SCAN_CHUNK)   // 49

typedef __bf16 bf16x8 __attribute__((ext_vector_type(8)));
typedef __bf16 bf16x4 __attribute__((ext_vector_type(4)));
typedef float  f32x4  __attribute__((ext_vector_type(4)));

__device__ __forceinline__ void cvt_store4(__bf16* p, float x, float y, float z, float w) {
    bf16x4 b = { (__bf16)x, (__bf16)y, (__bf16)z, (__bf16)w };
    *reinterpret_cast<bf16x4*>(p) = b;
}

// ---------------------------------------------------------------------------
// W (f32 [128,320]) -> bf16, once.  (kept separate — round-6 proven config)
// ---------------------------------------------------------------------------
__global__ __launch_bounds__(256) void wbf_kernel(const float* __restrict__ W,
                                                  __bf16* __restrict__ wbf) {
    int i = blockIdx.x * 256 + threadIdx.x;   // 160 blocks x 256 = 40960 exact
    wbf[i] = (__bf16)W[i];
}

// ---------------------------------------------------------------------------
// CSR build: histogram -> 3-kernel scan -> cursor-atomic fill (round-6 verbatim)
// ---------------------------------------------------------------------------
__global__ __launch_bounds__(256) void hist_kernel(const int* __restrict__ dst,
                                                   int* __restrict__ counts) {
    int i = blockIdx.x * 256 + threadIdx.x;   // 6250 x 256 = 1.6M exact
    if (i < N_EDGES) atomicAdd(&counts[dst[i]], 1);
}

__global__ __launch_bounds__(256) void scan1_kernel(const int* __restrict__ counts,
                                                    int* __restrict__ partial) {
    __shared__ int red[256];
    int tid = threadIdx.x;
    int base = blockIdx.x * SCAN_CHUNK + tid * 8;
    int s = 0;
    #pragma unroll
    for (int j = 0; j < 8; ++j) {
        int idx = base + j;
        if (idx < N_NODES) s += counts[idx];
    }
    red[tid] = s;
    __syncthreads();
    for (int off = 128; off > 0; off >>= 1) {
        if (tid < off) red[tid] += red[tid + off];
        __syncthreads();
    }
    if (tid == 0) partial[blockIdx.x] = red[0];
}

__global__ __launch_bounds__(64) void scan2_kernel(const int* __restrict__ partial,
                                                   int* __restrict__ pscan) {
    if (threadIdx.x == 0) {
        int run = 0;
        for (int b = 0; b < NSCAN; ++b) { pscan[b] = run; run += partial[b]; }
    }
}

__global__ __launch_bounds__(256) void scan3_kernel(const int* __restrict__ counts,
                                                    const int* __restrict__ pscan,
                                                    int* __restrict__ offs,
                                                    int* __restrict__ cursor) {
    __shared__ int ts[256];
    int tid = threadIdx.x;
    int base = blockIdx.x * SCAN_CHUNK + tid * 8;
    int c[8];
    int tot = 0;
    #pragma unroll
    for (int j = 0; j < 8; ++j) {
        int idx = base + j;
        c[j] = (idx < N_NODES) ? counts[idx] : 0;
        tot += c[j];
    }
    ts[tid] = tot;
    __syncthreads();
    for (int off = 1; off < 256; off <<= 1) {
        int v = 0;
        if (tid >= off) v = ts[tid - off];
        __syncthreads();
        if (tid >= off) ts[tid] += v;
        __syncthreads();
    }
    int run = pscan[blockIdx.x] + ts[tid] - tot;   // exclusive prefix
    #pragma unroll
    for (int j = 0; j < 8; ++j) {
        int idx = base + j;
        if (idx < N_NODES) { offs[idx] = run; cursor[idx] = run; run += c[j]; }
    }
    if (blockIdx.x == 0 && tid == 0) offs[N_NODES] = N_EDGES;
}

__global__ __launch_bounds__(256) void fill_kernel(const int* __restrict__ dst,
                                                   int* __restrict__ cursor,
                                                   int* __restrict__ eid) {
    int i = blockIdx.x * 256 + threadIdx.x;
    if (i < N_EDGES) {
        int d = dst[i];
        int pos = atomicAdd(&cursor[d], 1);
        eid[pos] = i;
    }
}

// ---------------------------------------------------------------------------
// Gather-mean kernel: 32-lane groups (2 nodes/wave), NO launch bounds
// (rounds 7/8 proved any VGPR cap kills the load pipeline). Each lane covers
// 16B of the 512B edge row -> 1 load per edge, 32 edges in flight per group.
// vs round 6 (16-lane groups): same bytes/coalescing, but wave straggler time
// is max(deg) over 2 nodes instead of 4. Writes mean as bf16 [N_NODES,128].
// ---------------------------------------------------------------------------
__global__ void gather_kernel(
    const float* __restrict__ edge_feats,   // [N_EDGES,128]
    const int*   __restrict__ offs,         // [N_NODES+1]
    const int*   __restrict__ eid,          // [N_EDGES]
    __bf16* __restrict__ mean_bf)           // [N_NODES,128]
{
    const int tid  = threadIdx.x;
    const int lane = tid & 63;
    const int g32  = lane & 31;             // lane within 32-group
    const int base = lane & 32;             // group base for shfl
    const int n    = blockIdx.x * 8 + (tid >> 5);   // node id, 12500 blocks exact

    const int beg = offs[n], end = offs[n + 1];
    const int E   = end - beg;
    const int lim = max(end - 1, 0);
    int ev = eid[min(beg + g32, lim)];      // 32 eids in flight

    float a0 = 0.f, a1 = 0.f, a2 = 0.f, a3 = 0.f;
    for (int c0 = 0; c0 < E; c0 += 32) {
        #pragma unroll
        for (int i = 0; i < 32; ++i) {
            int e = __shfl(ev, base + i);
            if (c0 + i < E) {
                f32x4 u = *reinterpret_cast<const f32x4*>(
                    edge_feats + (size_t)e * EDGE_F + g32 * 4);
                a0 += u.x; a1 += u.y; a2 += u.z; a3 += u.w;
            }
        }
        ev = eid[min(beg + c0 + 32 + g32, lim)];
    }
    float ic = 1.0f / fmaxf((float)E, 1.0f);
    bf16x4 b;
    b[0] = (__bf16)(a0 * ic); b[1] = (__bf16)(a1 * ic);
    b[2] = (__bf16)(a2 * ic); b[3] = (__bf16)(a3 * ic);
    *reinterpret_cast<bf16x4*>(mean_bf + (size_t)n * EDGE_F + g32 * 4) = b;
}

// ---------------------------------------------------------------------------
// GEMM kernel: concat (node f32->bf16, mean bf16 copy, glob f32->bf16) into
// LDS, barrier-free MFMA k-loop (B direct from L2-resident bf16 W), shifted
// softplus epilogue. Block = 256 threads (4 waves), 32 rows x 128 cols.
// ---------------------------------------------------------------------------
#define ROWS 32
#define XSTR (IN_DIM + 8)     // 328 bf16 -> 656 B row stride (16B-aligned)

__global__ __launch_bounds__(256) void gemm_kernel(
    const float* __restrict__ node_feats,   // [N_NODES,128]
    const __bf16* __restrict__ mean_bf,     // [N_NODES,128]
    const float* __restrict__ glob,         // [256,64]
    const int*   __restrict__ batch,        // [N_NODES]
    const __bf16* __restrict__ wbf,         // [128,320] bf16
    float* __restrict__ out)                // [N_NODES,128]
{
    __shared__ __bf16 xs[ROWS * XSTR];      // 20992 B

    const int tid  = threadIdx.x;
    const int row0 = blockIdx.x * ROWS;
    const int wv   = tid >> 6;
    const int lane = tid & 63;

    // ---- stage node features -> xs[:, 0:128)
    #pragma unroll
    for (int it = 0; it < 4; ++it) {
        int i = tid + it * 256;             // 0..1023
        int r = i >> 5, k4 = i & 31;
        float4 v = *reinterpret_cast<const float4*>(
            node_feats + (size_t)(row0 + r) * NODE_F + k4 * 4);
        cvt_store4(&xs[r * XSTR + k4 * 4], v.x, v.y, v.z, v.w);
    }
    // ---- stage mean (already bf16) -> xs[:, 128:256)
    #pragma unroll
    for (int it = 0; it < 2; ++it) {
        int i = tid + it * 256;             // 0..511
        int r = i >> 4, c = i & 15;
        bf16x8 v = *reinterpret_cast<const bf16x8*>(
            mean_bf + (size_t)(row0 + r) * EDGE_F + c * 8);
        *reinterpret_cast<bf16x8*>(&xs[r * XSTR + NODE_F + c * 8]) = v;
    }
    // ---- stage globals -> xs[:, 256:320)
    #pragma unroll
    for (int it = 0; it < 2; ++it) {
        int i = tid + it * 256;             // 0..511
        int r = i >> 4, k4 = i & 15;
        int b = batch[row0 + r];
        float4 v = *reinterpret_cast<const float4*>(
            glob + (size_t)b * GLOB_F + k4 * 4);
        cvt_store4(&xs[r * XSTR + NODE_F + EDGE_F + k4 * 4], v.x, v.y, v.z, v.w);
    }

    __syncthreads();   // xs complete; k-loop below is barrier-free

    f32x4 acc00 = {0.f, 0.f, 0.f, 0.f};
    f32x4 acc10 = {0.f, 0.f, 0.f, 0.f};
    f32x4 acc01 = {0.f, 0.f, 0.f, 0.f};
    f32x4 acc11 = {0.f, 0.f, 0.f, 0.f};

    const int lr = lane & 15;    // row/col within MFMA tile
    const int kb = lane >> 4;    // k-block of 8

    const __bf16* wrow0 = wbf + (size_t)(wv * 32 + lr) * IN_DIM + kb * 8;
    const __bf16* wrow1 = wrow0 + 16 * IN_DIM;

    #pragma unroll 2
    for (int kt = 0; kt < IN_DIM / 32; ++kt) {     // 10 k-steps
        bf16x8 a0 = *reinterpret_cast<const bf16x8*>(&xs[lr * XSTR + kt * 32 + kb * 8]);
        bf16x8 a1 = *reinterpret_cast<const bf16x8*>(&xs[(16 + lr) * XSTR + kt * 32 + kb * 8]);
        bf16x8 b0 = *reinterpret_cast<const bf16x8*>(wrow0 + kt * 32);
        bf16x8 b1 = *reinterpret_cast<const bf16x8*>(wrow1 + kt * 32);

        acc00 = __builtin_amdgcn_mfma_f32_16x16x32_bf16(a0, b0, acc00, 0, 0, 0);
        acc10 = __builtin_amdgcn_mfma_f32_16x16x32_bf16(a1, b0, acc10, 0, 0, 0);
        acc01 = __builtin_amdgcn_mfma_f32_16x16x32_bf16(a0, b1, acc01, 0, 0, 0);
        acc11 = __builtin_amdgcn_mfma_f32_16x16x32_bf16(a1, b1, acc11, 0, 0, 0);
    }

    // ---- epilogue: shifted softplus, C/D layout col=lane&15, row=(lane>>4)*4+q
    const float LN2 = 0.69314718055994530942f;
#define EMIT(ACC, RT, CT)                                                      \
    do {                                                                       \
        int col = (wv * 2 + (CT)) * 16 + lr;                                   \
        _Pragma("unroll")                                                      \
        for (int q = 0; q < 4; ++q) {                                          \
            int row = row0 + (RT) * 16 + kb * 4 + q;                           \
            float h = ACC[q];                                                  \
            float sp = fmaxf(h, 0.f) + log1pf(__expf(-fabsf(h)));              \
            out[(size_t)row * HIDDEN + col] = sp - LN2;                        \
        }                                                                      \
    } while (0)
    EMIT(acc00, 0, 0);
    EMIT(acc10, 1, 0);
    EMIT(acc01, 0, 1);
    EMIT(acc11, 1, 1);
#undef EMIT
}

// ---------------------------------------------------------------------------
extern "C" void kernel_launch(void* const* d_in, const int* in_sizes, int n_in,
                              void* d_out, int out_size, void* d_ws, size_t ws_size,
                              hipStream_t stream) {
    const float* node_feats = (const float*)d_in[0];   // [100000,128]
    const float* edge_feats = (const float*)d_in[1];   // [1600000,128]
    const float* glob       = (const float*)d_in[2];   // [256,64]
    const float* W          = (const float*)d_in[3];   // [128,320]
    const int*   edge_index = (const int*)d_in[4];     // [2,1600000]
    const int*   batch      = (const int*)d_in[5];     // [100000]
    float* out = (float*)d_out;                        // [100000,128]

    const int* dst = edge_index + N_EDGES;             // row 1 = destinations

    // workspace layout (16B-aligned chunks)
    __bf16* wbf     = (__bf16*)d_ws;                              // 81,920 B
    __bf16* mean_bf = (__bf16*)((char*)d_ws + 81920);             // 25,600,000 B
    int* ws_i       = (int*)((char*)d_ws + 81920 + 25600000);
    int* counts  = ws_i;                               // 100000
    int* partial = ws_i + 100000;                      // 64
    int* pscan   = ws_i + 100064;                      // 64
    int* offs    = ws_i + 100128;                      // 100001
    int* cursor  = ws_i + 200132;                      // 100000
    int* eid     = ws_i + 300132;                      // 1600000  (ends ~33 MB)

    hipMemsetAsync(counts, 0, (size_t)N_NODES * sizeof(int), stream);

    wbf_kernel<<<160, 256, 0, stream>>>(W, wbf);
    hist_kernel<<<N_EDGES / 256, 256, 0, stream>>>(dst, counts);
    scan1_kernel<<<NSCAN, 256, 0, stream>>>(counts, partial);
    scan2_kernel<<<1, 64, 0, stream>>>(partial, pscan);
    scan3_kernel<<<NSCAN, 256, 0, stream>>>(counts, pscan, offs, cursor);
    fill_kernel<<<N_EDGES / 256, 256, 0, stream>>>(dst, cursor, eid);

    gather_kernel<<<N_NODES / 8, 256, 0, stream>>>(edge_feats, offs, eid, mean_bf);

    gemm_kernel<<<N_NODES / ROWS, 256, 0, stream>>>(
        node_feats, mean_bf, glob, batch, wbf, out);
}

// Round 11
// 451.438 us; speedup vs baseline: 1.0190x; 1.0062x over previous
//
#include <hip/hip_runtime.h>
#include <math.h>

#define N_NODES   100000
#define N_EDGES   1600000
#define NODE_F    128
#define EDGE_F    128
#define GLOB_F    64
#define N_GRAPHS  256
#define HIDDEN    128
#define IN_DIM    320   // 128 + 128 + 64

#define SCAN_CHUNK 2048
#define NSCAN ((N_NODES + SCAN_CHUNK - 1) / SCAN_CHUNK)   // 49

typedef __bf16 bf16x8 __attribute__((ext_vector_type(8)));
typedef __bf16 bf16x4 __attribute__((ext_vector_type(4)));
typedef float  f32x4  __attribute__((ext_vector_type(4)));

__device__ __forceinline__ void cvt_store4(__bf16* p, float x, float y, float z, float w) {
    bf16x4 b = { (__bf16)x, (__bf16)y, (__bf16)z, (__bf16)w };
    *reinterpret_cast<bf16x4*>(p) = b;
}

// ---------------------------------------------------------------------------
// W (f32 [128,320]) -> bf16, once.
// ---------------------------------------------------------------------------
__global__ __launch_bounds__(256) void wbf_kernel(const float* __restrict__ W,
                                                  __bf16* __restrict__ wbf) {
    int i = blockIdx.x * 256 + threadIdx.x;   // 160 blocks x 256 = 40960 exact
    wbf[i] = (__bf16)W[i];
}

// ---------------------------------------------------------------------------
// CSR build: histogram -> 3-kernel scan -> cursor-atomic fill
// ---------------------------------------------------------------------------
__global__ __launch_bounds__(256) void hist_kernel(const int* __restrict__ dst,
                                                   int* __restrict__ counts) {
    int i = blockIdx.x * 256 + threadIdx.x;   // 6250 x 256 = 1.6M exact
    if (i < N_EDGES) atomicAdd(&counts[dst[i]], 1);
}

__global__ __launch_bounds__(256) void scan1_kernel(const int* __restrict__ counts,
                                                    int* __restrict__ partial) {
    __shared__ int red[256];
    int tid = threadIdx.x;
    int base = blockIdx.x * SCAN_CHUNK + tid * 8;
    int s = 0;
    #pragma unroll
    for (int j = 0; j < 8; ++j) {
        int idx = base + j;
        if (idx < N_NODES) s += counts[idx];
    }
    red[tid] = s;
    __syncthreads();
    for (int off = 128; off > 0; off >>= 1) {
        if (tid < off) red[tid] += red[tid + off];
        __syncthreads();
    }
    if (tid == 0) partial[blockIdx.x] = red[0];
}

__global__ __launch_bounds__(64) void scan2_kernel(const int* __restrict__ partial,
                                                   int* __restrict__ pscan) {
    if (threadIdx.x == 0) {
        int run = 0;
        for (int b = 0; b < NSCAN; ++b) { pscan[b] = run; run += partial[b]; }
    }
}

__global__ __launch_bounds__(256) void scan3_kernel(const int* __restrict__ counts,
                                                    const int* __restrict__ pscan,
                                                    int* __restrict__ offs,
                                                    int* __restrict__ cursor) {
    __shared__ int ts[256];
    int tid = threadIdx.x;
    int base = blockIdx.x * SCAN_CHUNK + tid * 8;
    int c[8];
    int tot = 0;
    #pragma unroll
    for (int j = 0; j < 8; ++j) {
        int idx = base + j;
        c[j] = (idx < N_NODES) ? counts[idx] : 0;
        tot += c[j];
    }
    ts[tid] = tot;
    __syncthreads();
    for (int off = 1; off < 256; off <<= 1) {
        int v = 0;
        if (tid >= off) v = ts[tid - off];
        __syncthreads();
        if (tid >= off) ts[tid] += v;
        __syncthreads();
    }
    int run = pscan[blockIdx.x] + ts[tid] - tot;   // exclusive prefix
    #pragma unroll
    for (int j = 0; j < 8; ++j) {
        int idx = base + j;
        if (idx < N_NODES) { offs[idx] = run; cursor[idx] = run; run += c[j]; }
    }
    if (blockIdx.x == 0 && tid == 0) offs[N_NODES] = N_EDGES;
}

__global__ __launch_bounds__(256) void fill_kernel(const int* __restrict__ dst,
                                                   int* __restrict__ cursor,
                                                   int* __restrict__ eid) {
    int i = blockIdx.x * 256 + threadIdx.x;
    if (i < N_EDGES) {
        int d = dst[i];
        int pos = atomicAdd(&cursor[d], 1);
        eid[pos] = i;
    }
}

// ---------------------------------------------------------------------------
// Gather-mean kernel (dedicated, high-occupancy): one node per 16-lane group,
// 16 groups per 256-thread block, zero LDS, small VGPR footprint.
// Writes mean as bf16 [N_NODES,128] (coalesced 256B per group).
// NOTE: uncapped occupancy (no min-waves arg) is deliberate — rounds 7/8
// proved any VGPR cap (64 or 128) serializes the load pipeline and costs
// ~100 us; 32-lane groups (round 9) also regressed. This exact shape = 350 us.
// ---------------------------------------------------------------------------
__global__ __launch_bounds__(256, 6) void gather_kernel(
    const float* __restrict__ edge_feats,   // [N_EDGES,128]
    const int*   __restrict__ offs,         // [N_NODES+1]
    const int*   __restrict__ eid,          // [N_EDGES]
    __bf16* __restrict__ mean_bf)           // [N_NODES,128]
{
    const int tid  = threadIdx.x;
    const int lane = tid & 63;
    const int gl   = lane & 15;             // lane within 16-group
    const int n    = blockIdx.x * 16 + (tid >> 4);   // node id, 6250 blocks exact

    const int beg = offs[n], end = offs[n + 1];
    const int E   = end - beg;
    const int lim = max(end - 1, 0);
    int ev = eid[min(beg + gl, lim)];

    float a0=0.f,a1=0.f,a2=0.f,a3=0.f,a4=0.f,a5=0.f,a6=0.f,a7=0.f;
    for (int c0 = 0; c0 < E; c0 += 16) {
        #pragma unroll
        for (int i = 0; i < 16; ++i) {
            int e = __shfl(ev, (lane & 48) + i);
            if (c0 + i < E) {
                const f32x4* p = reinterpret_cast<const f32x4*>(
                    edge_feats + (size_t)e * EDGE_F + gl * 8);
                f32x4 u0 = p[0];
                f32x4 u1 = p[1];
                a0 += u0.x; a1 += u0.y; a2 += u0.z; a3 += u0.w;
                a4 += u1.x; a5 += u1.y; a6 += u1.z; a7 += u1.w;
            }
        }
        ev = eid[min(beg + c0 + 16 + gl, lim)];
    }
    float ic = 1.0f / fmaxf((float)E, 1.0f);
    bf16x8 b;
    b[0]=(__bf16)(a0*ic); b[1]=(__bf16)(a1*ic);
    b[2]=(__bf16)(a2*ic); b[3]=(__bf16)(a3*ic);
    b[4]=(__bf16)(a4*ic); b[5]=(__bf16)(a5*ic);
    b[6]=(__bf16)(a6*ic); b[7]=(__bf16)(a7*ic);
    *reinterpret_cast<bf16x8*>(mean_bf + (size_t)n * EDGE_F + gl * 8) = b;
}

// ---------------------------------------------------------------------------
// GEMM kernel: concat (node f32->bf16, mean bf16 copy, glob f32->bf16) into
// LDS, barrier-free MFMA k-loop (B direct from L2-resident bf16 W), shifted
// softplus epilogue. Block = 256 threads (4 waves), 32 rows x 128 cols.
// ---------------------------------------------------------------------------
#define ROWS 32
#define XSTR (IN_DIM + 8)     // 328 bf16 -> 656 B row stride (16B-aligned)

__global__ __launch_bounds__(256) void gemm_kernel(
    const float* __restrict__ node_feats,   // [N_NODES,128]
    const __bf16* __restrict__ mean_bf,     // [N_NODES,128]
    const float* __restrict__ glob,         // [256,64]
    const int*   __restrict__ batch,        // [N_NODES]
    const __bf16* __restrict__ wbf,         // [128,320] bf16
    float* __restrict__ out)                // [N_NODES,128]
{
    __shared__ __bf16 xs[ROWS * XSTR];      // 20992 B

    const int tid  = threadIdx.x;
    const int row0 = blockIdx.x * ROWS;
    const int wv   = tid >> 6;
    const int lane = tid & 63;

    // ---- stage node features -> xs[:, 0:128)
    #pragma unroll
    for (int it = 0; it < 4; ++it) {
        int i = tid + it * 256;             // 0..1023
        int r = i >> 5, k4 = i & 31;
        float4 v = *reinterpret_cast<const float4*>(
            node_feats + (size_t)(row0 + r) * NODE_F + k4 * 4);
        cvt_store4(&xs[r * XSTR + k4 * 4], v.x, v.y, v.z, v.w);
    }
    // ---- stage mean (already bf16) -> xs[:, 128:256)
    #pragma unroll
    for (int it = 0; it < 2; ++it) {
        int i = tid + it * 256;             // 0..511
        int r = i >> 4, c = i & 15;
        bf16x8 v = *reinterpret_cast<const bf16x8*>(
            mean_bf + (size_t)(row0 + r) * EDGE_F + c * 8);
        *reinterpret_cast<bf16x8*>(&xs[r * XSTR + NODE_F + c * 8]) = v;
    }
    // ---- stage globals -> xs[:, 256:320)
    #pragma unroll
    for (int it = 0; it < 2; ++it) {
        int i = tid + it * 256;             // 0..511
        int r = i >> 4, k4 = i & 15;
        int b = batch[row0 + r];
        float4 v = *reinterpret_cast<const float4*>(
            glob + (size_t)b * GLOB_F + k4 * 4);
        cvt_store4(&xs[r * XSTR + NODE_F + EDGE_F + k4 * 4], v.x, v.y, v.z, v.w);
    }

    __syncthreads();   // xs complete; k-loop below is barrier-free

    f32x4 acc00 = {0.f, 0.f, 0.f, 0.f};
    f32x4 acc10 = {0.f, 0.f, 0.f, 0.f};
    f32x4 acc01 = {0.f, 0.f, 0.f, 0.f};
    f32x4 acc11 = {0.f, 0.f, 0.f, 0.f};

    const int lr = lane & 15;    // row/col within MFMA tile
    const int kb = lane >> 4;    // k-block of 8

    const __bf16* wrow0 = wbf + (size_t)(wv * 32 + lr) * IN_DIM + kb * 8;
    const __bf16* wrow1 = wrow0 + 16 * IN_DIM;

    #pragma unroll 2
    for (int kt = 0; kt < IN_DIM / 32; ++kt) {     // 10 k-steps
        bf16x8 a0 = *reinterpret_cast<const bf16x8*>(&xs[lr * XSTR + kt * 32 + kb * 8]);
        bf16x8 a1 = *reinterpret_cast<const bf16x8*>(&xs[(16 + lr) * XSTR + kt * 32 + kb * 8]);
        bf16x8 b0 = *reinterpret_cast<const bf16x8*>(wrow0 + kt * 32);
        bf16x8 b1 = *reinterpret_cast<const bf16x8*>(wrow1 + kt * 32);

        acc00 = __builtin_amdgcn_mfma_f32_16x16x32_bf16(a0, b0, acc00, 0, 0, 0);
        acc10 = __builtin_amdgcn_mfma_f32_16x16x32_bf16(a1, b0, acc10, 0, 0, 0);
        acc01 = __builtin_amdgcn_mfma_f32_16x16x32_bf16(a0, b1, acc01, 0, 0, 0);
        acc11 = __builtin_amdgcn_mfma_f32_16x16x32_bf16(a1, b1, acc11, 0, 0, 0);
    }

    // ---- epilogue: shifted softplus, C/D layout col=lane&15, row=(lane>>4)*4+q
    const float LN2 = 0.69314718055994530942f;
#define EMIT(ACC, RT, CT)                                                      \
    do {                                                                       \
        int col = (wv * 2 + (CT)) * 16 + lr;                                   \
        _Pragma("unroll")                                                      \
        for (int q = 0; q < 4; ++q) {                                          \
            int row = row0 + (RT) * 16 + kb * 4 + q;                           \
            float h = ACC[q];                                                  \
            float sp = fmaxf(h, 0.f) + log1pf(__expf(-fabsf(h)));              \
            out[(size_t)row * HIDDEN + col] = sp - LN2;                        \
        }                                                                      \
    } while (0)
    EMIT(acc00, 0, 0);
    EMIT(acc10, 1, 0);
    EMIT(acc01, 0, 1);
    EMIT(acc11, 1, 1);
#undef EMIT
}

// ---------------------------------------------------------------------------
extern "C" void kernel_launch(void* const* d_in, const int* in_sizes, int n_in,
                              void* d_out, int out_size, void* d_ws, size_t ws_size,
                              hipStream_t stream) {
    const float* node_feats = (const float*)d_in[0];   // [100000,128]
    const float* edge_feats = (const float*)d_in[1];   // [1600000,128]
    const float* glob       = (const float*)d_in[2];   // [256,64]
    const float* W          = (const float*)d_in[3];   // [128,320]
    const int*   edge_index = (const int*)d_in[4];     // [2,1600000]
    const int*   batch      = (const int*)d_in[5];     // [100000]
    float* out = (float*)d_out;                        // [100000,128]

    const int* dst = edge_index + N_EDGES;             // row 1 = destinations

    // workspace layout (16B-aligned chunks)
    __bf16* wbf     = (__bf16*)d_ws;                              // 81,920 B
    __bf16* mean_bf = (__bf16*)((char*)d_ws + 81920);             // 25,600,000 B
    int* ws_i       = (int*)((char*)d_ws + 81920 + 25600000);
    int* counts  = ws_i;                               // 100000
    int* partial = ws_i + 100000;                      // 64
    int* pscan   = ws_i + 100064;                      // 64
    int* offs    = ws_i + 100128;                      // 100001
    int* cursor  = ws_i + 200132;                      // 100000
    int* eid     = ws_i + 300132;                      // 1600000  (ends ~33 MB)

    hipMemsetAsync(counts, 0, (size_t)N_NODES * sizeof(int), stream);

    wbf_kernel<<<160, 256, 0, stream>>>(W, wbf);
    hist_kernel<<<N_EDGES / 256, 256, 0, stream>>>(dst, counts);
    scan1_kernel<<<NSCAN, 256, 0, stream>>>(counts, partial);
    scan2_kernel<<<1, 64, 0, stream>>>(partial, pscan);
    scan3_kernel<<<NSCAN, 256, 0, stream>>>(counts, pscan, offs, cursor);
    fill_kernel<<<N_EDGES / 256, 256, 0, stream>>>(dst, cursor, eid);

    gather_kernel<<<N_NODES / 16, 256, 0, stream>>>(edge_feats, offs, eid, mean_bf);

    gemm_kernel<<<N_NODES / ROWS, 256, 0, stream>>>(
        node_feats, mean_bf, glob, batch, wbf, out);
}

// Round 12
// 349.205 us; speedup vs baseline: 1.3173x; 1.2928x over previous
//
#include <hip/hip_runtime.h>
#include <math.h>

#define N_NODES   100000
#define N_EDGES   1600000
#define NODE_F    128
#define EDGE_F    128
#define GLOB_F    64
#define N_GRAPHS  256
#define HIDDEN    128
#define IN_DIM    320   // 128 + 128 + 64

#define SCAN_CHUNK 2048
#define NSCAN ((N_NODES + SCAN_CHUNK - 1) / SCAN_CHUNK)   // 49

typedef __bf16 bf16x8 __attribute__((ext_vector_type(8)));
typedef __bf16 bf16x4 __attribute__((ext_vector_type(4)));
typedef float  f32x4  __attribute__((ext_vector_type(4)));

__device__ __forceinline__ void cvt_store4(__bf16* p, float x, float y, float z, float w) {
    bf16x4 b = { (__bf16)x, (__bf16)y, (__bf16)z, (__bf16)w };
    *reinterpret_cast<bf16x4*>(p) = b;
}

// ---------------------------------------------------------------------------
// W (f32 [128,320]) -> bf16, once.
// ---------------------------------------------------------------------------
__global__ __launch_bounds__(256) void wbf_kernel(const float* __restrict__ W,
                                                  __bf16* __restrict__ wbf) {
    int i = blockIdx.x * 256 + threadIdx.x;   // 160 blocks x 256 = 40960 exact
    wbf[i] = (__bf16)W[i];
}

// ---------------------------------------------------------------------------
// CSR build: histogram(+rank) -> 3-kernel scan -> rank fill (atomic-free)
// ---------------------------------------------------------------------------
__global__ __launch_bounds__(256) void hist_kernel(const int* __restrict__ dst,
                                                   int* __restrict__ counts,
                                                   int* __restrict__ rank) {
    int i = blockIdx.x * 256 + threadIdx.x;   // 6250 x 256 = 1.6M exact
    if (i < N_EDGES) rank[i] = atomicAdd(&counts[dst[i]], 1);
}

__global__ __launch_bounds__(256) void scan1_kernel(const int* __restrict__ counts,
                                                    int* __restrict__ partial) {
    __shared__ int red[256];
    int tid = threadIdx.x;
    int base = blockIdx.x * SCAN_CHUNK + tid * 8;
    int s = 0;
    #pragma unroll
    for (int j = 0; j < 8; ++j) {
        int idx = base + j;
        if (idx < N_NODES) s += counts[idx];
    }
    red[tid] = s;
    __syncthreads();
    for (int off = 128; off > 0; off >>= 1) {
        if (tid < off) red[tid] += red[tid + off];
        __syncthreads();
    }
    if (tid == 0) partial[blockIdx.x] = red[0];
}

__global__ __launch_bounds__(64) void scan2_kernel(const int* __restrict__ partial,
                                                   int* __restrict__ pscan) {
    if (threadIdx.x == 0) {
        int run = 0;
        for (int b = 0; b < NSCAN; ++b) { pscan[b] = run; run += partial[b]; }
    }
}

__global__ __launch_bounds__(256) void scan3_kernel(const int* __restrict__ counts,
                                                    const int* __restrict__ pscan,
                                                    int* __restrict__ offs) {
    __shared__ int ts[256];
    int tid = threadIdx.x;
    int base = blockIdx.x * SCAN_CHUNK + tid * 8;
    int c[8];
    int tot = 0;
    #pragma unroll
    for (int j = 0; j < 8; ++j) {
        int idx = base + j;
        c[j] = (idx < N_NODES) ? counts[idx] : 0;
        tot += c[j];
    }
    ts[tid] = tot;
    __syncthreads();
    for (int off = 1; off < 256; off <<= 1) {
        int v = 0;
        if (tid >= off) v = ts[tid - off];
        __syncthreads();
        if (tid >= off) ts[tid] += v;
        __syncthreads();
    }
    int run = pscan[blockIdx.x] + ts[tid] - tot;   // exclusive prefix
    #pragma unroll
    for (int j = 0; j < 8; ++j) {
        int idx = base + j;
        if (idx < N_NODES) { offs[idx] = run; run += c[j]; }
    }
    if (blockIdx.x == 0 && tid == 0) offs[N_NODES] = N_EDGES;
}

__global__ __launch_bounds__(256) void fill_kernel(const int* __restrict__ dst,
                                                   const int* __restrict__ rank,
                                                   const int* __restrict__ offs,
                                                   int* __restrict__ eid) {
    int i = blockIdx.x * 256 + threadIdx.x;
    if (i < N_EDGES) {
        int d = dst[i];
        eid[offs[d] + rank[i]] = i;
    }
}

// ---------------------------------------------------------------------------
// Gather-mean kernel (dedicated, high-occupancy): one node per 16-lane group,
// 16 groups per 256-thread block, zero LDS, small VGPR footprint.
// Writes mean as bf16 [N_NODES,128] (coalesced 256B per group).
// ---------------------------------------------------------------------------
__global__ __launch_bounds__(256, 6) void gather_kernel(
    const float* __restrict__ edge_feats,   // [N_EDGES,128]
    const int*   __restrict__ offs,         // [N_NODES+1]
    const int*   __restrict__ eid,          // [N_EDGES]
    __bf16* __restrict__ mean_bf)           // [N_NODES,128]
{
    const int tid  = threadIdx.x;
    const int lane = tid & 63;
    const int gl   = lane & 15;             // lane within 16-group
    const int n    = blockIdx.x * 16 + (tid >> 4);   // node id, 6250 blocks exact

    const int beg = offs[n], end = offs[n + 1];
    const int E   = end - beg;
    const int lim = max(end - 1, 0);
    int ev = eid[min(beg + gl, lim)];

    float a0=0.f,a1=0.f,a2=0.f,a3=0.f,a4=0.f,a5=0.f,a6=0.f,a7=0.f;
    for (int c0 = 0; c0 < E; c0 += 16) {
        #pragma unroll
        for (int i = 0; i < 16; ++i) {
            int e = __shfl(ev, (lane & 48) + i);
            if (c0 + i < E) {
                const f32x4* p = reinterpret_cast<const f32x4*>(
                    edge_feats + (size_t)e * EDGE_F + gl * 8);
                f32x4 u0 = p[0];
                f32x4 u1 = p[1];
                a0 += u0.x; a1 += u0.y; a2 += u0.z; a3 += u0.w;
                a4 += u1.x; a5 += u1.y; a6 += u1.z; a7 += u1.w;
            }
        }
        ev = eid[min(beg + c0 + 16 + gl, lim)];
    }
    float ic = 1.0f / fmaxf((float)E, 1.0f);
    bf16x8 b;
    b[0]=(__bf16)(a0*ic); b[1]=(__bf16)(a1*ic);
    b[2]=(__bf16)(a2*ic); b[3]=(__bf16)(a3*ic);
    b[4]=(__bf16)(a4*ic); b[5]=(__bf16)(a5*ic);
    b[6]=(__bf16)(a6*ic); b[7]=(__bf16)(a7*ic);
    *reinterpret_cast<bf16x8*>(mean_bf + (size_t)n * EDGE_F + gl * 8) = b;
}

// ---------------------------------------------------------------------------
// GEMM kernel: concat (node f32->bf16, mean bf16 copy, glob f32->bf16) into
// LDS, barrier-free MFMA k-loop (B direct from L2-resident bf16 W), shifted
// softplus epilogue. Block = 256 threads (4 waves), 32 rows x 128 cols.
// ---------------------------------------------------------------------------
#define ROWS 32
#define XSTR (IN_DIM + 8)     // 328 bf16 -> 656 B row stride (16B-aligned)

__global__ __launch_bounds__(256) void gemm_kernel(
    const float* __restrict__ node_feats,   // [N_NODES,128]
    const __bf16* __restrict__ mean_bf,     // [N_NODES,128]
    const float* __restrict__ glob,         // [256,64]
    const int*   __restrict__ batch,        // [N_NODES]
    const __bf16* __restrict__ wbf,         // [128,320] bf16
    float* __restrict__ out)                // [N_NODES,128]
{
    __shared__ __bf16 xs[ROWS * XSTR];      // 20992 B

    const int tid  = threadIdx.x;
    const int row0 = blockIdx.x * ROWS;
    const int wv   = tid >> 6;
    const int lane = tid & 63;

    // ---- stage node features -> xs[:, 0:128)
    #pragma unroll
    for (int it = 0; it < 4; ++it) {
        int i = tid + it * 256;             // 0..1023
        int r = i >> 5, k4 = i & 31;
        float4 v = *reinterpret_cast<const float4*>(
            node_feats + (size_t)(row0 + r) * NODE_F + k4 * 4);
        cvt_store4(&xs[r * XSTR + k4 * 4], v.x, v.y, v.z, v.w);
    }
    // ---- stage mean (already bf16) -> xs[:, 128:256)
    #pragma unroll
    for (int it = 0; it < 2; ++it) {
        int i = tid + it * 256;             // 0..511
        int r = i >> 4, c = i & 15;
        bf16x8 v = *reinterpret_cast<const bf16x8*>(
            mean_bf + (size_t)(row0 + r) * EDGE_F + c * 8);
        *reinterpret_cast<bf16x8*>(&xs[r * XSTR + NODE_F + c * 8]) = v;
    }
    // ---- stage globals -> xs[:, 256:320)
    #pragma unroll
    for (int it = 0; it < 2; ++it) {
        int i = tid + it * 256;             // 0..511
        int r = i >> 4, k4 = i & 15;
        int b = batch[row0 + r];
        float4 v = *reinterpret_cast<const float4*>(
            glob + (size_t)b * GLOB_F + k4 * 4);
        cvt_store4(&xs[r * XSTR + NODE_F + EDGE_F + k4 * 4], v.x, v.y, v.z, v.w);
    }

    __syncthreads();   // xs complete; k-loop below is barrier-free

    f32x4 acc00 = {0.f, 0.f, 0.f, 0.f};
    f32x4 acc10 = {0.f, 0.f, 0.f, 0.f};
    f32x4 acc01 = {0.f, 0.f, 0.f, 0.f};
    f32x4 acc11 = {0.f, 0.f, 0.f, 0.f};

    const int lr = lane & 15;    // row/col within MFMA tile
    const int kb = lane >> 4;    // k-block of 8

    const __bf16* wrow0 = wbf + (size_t)(wv * 32 + lr) * IN_DIM + kb * 8;
    const __bf16* wrow1 = wrow0 + 16 * IN_DIM;

    #pragma unroll 2
    for (int kt = 0; kt < IN_DIM / 32; ++kt) {     // 10 k-steps
        bf16x8 a0 = *reinterpret_cast<const bf16x8*>(&xs[lr * XSTR + kt * 32 + kb * 8]);
        bf16x8 a1 = *reinterpret_cast<const bf16x8*>(&xs[(16 + lr) * XSTR + kt * 32 + kb * 8]);
        bf16x8 b0 = *reinterpret_cast<const bf16x8*>(wrow0 + kt * 32);
        bf16x8 b1 = *reinterpret_cast<const bf16x8*>(wrow1 + kt * 32);

        acc00 = __builtin_amdgcn_mfma_f32_16x16x32_bf16(a0, b0, acc00, 0, 0, 0);
        acc10 = __builtin_amdgcn_mfma_f32_16x16x32_bf16(a1, b0, acc10, 0, 0, 0);
        acc01 = __builtin_amdgcn_mfma_f32_16x16x32_bf16(a0, b1, acc01, 0, 0, 0);
        acc11 = __builtin_amdgcn_mfma_f32_16x16x32_bf16(a1, b1, acc11, 0, 0, 0);
    }

    // ---- epilogue: shifted softplus, C/D layout col=lane&15, row=(lane>>4)*4+q
    const float LN2 = 0.69314718055994530942f;
#define EMIT(ACC, RT, CT)                                                      \
    do {                                                                       \
        int col = (wv * 2 + (CT)) * 16 + lr;                                   \
        _Pragma("unroll")                                                      \
        for (int q = 0; q < 4; ++q) {                                          \
            int row = row0 + (RT) * 16 + kb * 4 + q;                           \
            float h = ACC[q];                                                  \
            float sp = fmaxf(h, 0.f) + log1pf(__expf(-fabsf(h)));              \
            out[(size_t)row * HIDDEN + col] = sp - LN2;                        \
        }                                                                      \
    } while (0)
    EMIT(acc00, 0, 0);
    EMIT(acc10, 1, 0);
    EMIT(acc01, 0, 1);
    EMIT(acc11, 1, 1);
#undef EMIT
}

// ---------------------------------------------------------------------------
extern "C" void kernel_launch(void* const* d_in, const int* in_sizes, int n_in,
                              void* d_out, int out_size, void* d_ws, size_t ws_size,
                              hipStream_t stream) {
    const float* node_feats = (const float*)d_in[0];   // [100000,128]
    const float* edge_feats = (const float*)d_in[1];   // [1600000,128]
    const float* glob       = (const float*)d_in[2];   // [256,64]
    const float* W          = (const float*)d_in[3];   // [128,320]
    const int*   edge_index = (const int*)d_in[4];     // [2,1600000]
    const int*   batch      = (const int*)d_in[5];     // [100000]
    float* out = (float*)d_out;                        // [100000,128]

    const int* dst = edge_index + N_EDGES;             // row 1 = destinations

    // workspace layout (16B-aligned chunks)
    __bf16* wbf     = (__bf16*)d_ws;                              // 81,920 B
    __bf16* mean_bf = (__bf16*)((char*)d_ws + 81920);             // 25,600,000 B
    int* ws_i       = (int*)((char*)d_ws + 81920 + 25600000);
    int* counts  = ws_i;                               // 100000
    int* partial = ws_i + 100000;                      // 64
    int* pscan   = ws_i + 100064;                      // 64
    int* offs    = ws_i + 100128;                      // 100001
    int* eid     = ws_i + 200132;                      // 1600000
    int* rank    = ws_i + 1800132;                     // 1600000  (ends ~39 MB)

    hipMemsetAsync(counts, 0, (size_t)N_NODES * sizeof(int), stream);

    wbf_kernel<<<160, 256, 0, stream>>>(W, wbf);
    hist_kernel<<<N_EDGES / 256, 256, 0, stream>>>(dst, counts, rank);
    scan1_kernel<<<NSCAN, 256, 0, stream>>>(counts, partial);
    scan2_kernel<<<1, 64, 0, stream>>>(partial, pscan);
    scan3_kernel<<<NSCAN, 256, 0, stream>>>(counts, pscan, offs);
    fill_kernel<<<N_EDGES / 256, 256, 0, stream>>>(dst, rank, offs, eid);

    gather_kernel<<<N_NODES / 16, 256, 0, stream>>>(edge_feats, offs, eid, mean_bf);

    gemm_kernel<<<N_NODES / ROWS, 256, 0, stream>>>(
        node_feats, mean_bf, glob, batch, wbf, out);
}